// Round 1
// 1844.852 us; speedup vs baseline: 1.2764x; 1.2764x over previous
//
#include <hip/hip_runtime.h>
#include <cstddef>
#include <cstdint>
#include <math.h>

#define BB   4
#define TT   2048
#define CCH  1024
#define HH   16
#define DD   64
#define CSZ  16
#define NTC  128
#define EPSF 1e-5f

__device__ __forceinline__ float wave_sum(float v) {
#pragma unroll
  for (int off = 32; off > 0; off >>= 1) v += __shfl_xor(v, off, 64);
  return v;
}

__device__ __forceinline__ float sigmoidf_(float x) {
  return 1.f / (1.f + expf(-x));
}

// C = A(lda) @ W + bias ; A: MxK row-major w/ stride lda, W: KxN row-major, C: MxN (ldc = N)
// M % 128 == 0, K % 16 == 0. N bounds-checked.
__global__ __launch_bounds__(256) void gemm_f32(
    const float* __restrict__ A, int lda,
    const float* __restrict__ W,
    const float* __restrict__ bias,
    float* __restrict__ C, int M, int N, int K) {
  __shared__ float As[16][132];   // [k][m], padded to break store conflicts
  __shared__ float Bs[16][128];   // [k][n]
  const int tid  = threadIdx.x;
  const int row0 = blockIdx.y * 128;
  const int col0 = blockIdx.x * 128;
  const int ty = tid >> 4;         // 0..15 (m dir)
  const int tx = tid & 15;         // 0..15 (n dir)
  const int a_r = tid >> 2;        // 0..63
  const int a_k = (tid & 3) << 2;  // 0,4,8,12
  const int b_r = tid >> 5;        // 0..7
  const int b_c = (tid & 31) << 2; // 0..124

  float acc[8][8];
#pragma unroll
  for (int i = 0; i < 8; i++)
#pragma unroll
    for (int j = 0; j < 8; j++) acc[i][j] = 0.f;

  for (int k0 = 0; k0 < K; k0 += 16) {
#pragma unroll
    for (int i = 0; i < 2; i++) {
      int r = a_r + i * 64;
      float4 av = *(const float4*)(A + (size_t)(row0 + r) * lda + (k0 + a_k));
      As[a_k + 0][r] = av.x;
      As[a_k + 1][r] = av.y;
      As[a_k + 2][r] = av.z;
      As[a_k + 3][r] = av.w;
    }
#pragma unroll
    for (int i = 0; i < 2; i++) {
      int r = b_r + i * 8;
      int gc = col0 + b_c;
      float4 bv = make_float4(0.f, 0.f, 0.f, 0.f);
      if (gc < N) bv = *(const float4*)(W + (size_t)(k0 + r) * N + gc);
      *(float4*)(&Bs[r][b_c]) = bv;
    }
    __syncthreads();
#pragma unroll
    for (int kk = 0; kk < 16; kk++) {
      float af[8], bf[8];
      *(float4*)&af[0] = *(const float4*)&As[kk][ty * 8];
      *(float4*)&af[4] = *(const float4*)&As[kk][ty * 8 + 4];
      *(float4*)&bf[0] = *(const float4*)&Bs[kk][tx * 8];
      *(float4*)&bf[4] = *(const float4*)&Bs[kk][tx * 8 + 4];
#pragma unroll
      for (int i = 0; i < 8; i++)
#pragma unroll
        for (int j = 0; j < 8; j++) acc[i][j] += af[i] * bf[j];
    }
    __syncthreads();
  }
#pragma unroll
  for (int i = 0; i < 8; i++) {
    int r = row0 + ty * 8 + i;
#pragma unroll
    for (int j0 = 0; j0 < 8; j0 += 4) {
      int cc = col0 + tx * 8 + j0;
      if (cc < N) {
        float4 ov;
        ov.x = acc[i][j0 + 0] + bias[cc + 0];
        ov.y = acc[i][j0 + 1] + bias[cc + 1];
        ov.z = acc[i][j0 + 2] + bias[cc + 2];
        ov.w = acc[i][j0 + 3] + bias[cc + 3];
        *(float4*)(C + (size_t)r * N + cc) = ov;
      }
    }
  }
}

// L2-normalize q and k rows (length 64) in-place inside the qkv buffer.
// One wave per row. rows = B*T*2*H.
__global__ __launch_bounds__(256) void normalize_qk(float* __restrict__ qkv) {
  const int idx = blockIdx.x * 4 + (threadIdx.x >> 6);
  const int l = threadIdx.x & 63;
  const int rowBT = idx >> 5;        // / (2*H)
  const int rem = idx & 31;
  const int which = rem >> 4;        // 0 = q, 1 = k
  const int h = rem & 15;
  const size_t addr = (size_t)rowBT * 3072 + (size_t)which * 1024 + h * 64 + l;
  float v = qkv[addr];
  float ss = wave_sum(v * v);
  float nrm = sqrtf(ss);
  float sc = 1.f / fmaxf(nrm, 1e-12f);
  qkv[addr] = v * sc;
}

// Titans recurrence. One block per (b,h). 1024 threads = 16 waves (4 waves/SIMD
// for latency hiding; the old 256-thread version ran 1 wave/SIMD and sat 93% stalled).
// Thread (wv = tid/64, l = tid%64) owns S[wv*4+r][l], M[wv*4+r][l] (r=0..3) in registers.
// Next chunk's q/k/v/p tiles are prefetched into registers at phase A and committed to
// LDS during phase D, hiding global-load latency under the compute phases.
// Writes LN(o) into the (consumed) v-slot of qkv: col offset 2048.
__global__ __launch_bounds__(1024) void titans_rec(
    float* __restrict__ qkv, const float* __restrict__ p,
    const float* __restrict__ w, const float* __restrict__ bparm) {
  const int bh = blockIdx.x;
  const int b = bh >> 4;
  const int h = bh & 15;
  const int tid = threadIdx.x;
  const int wv = tid >> 6;   // 0..15
  const int l = tid & 63;

  __shared__ float k_s[CSZ][DD];
  __shared__ float v_s[CSZ][DD];
  __shared__ float q_s[CSZ][DD];
  __shared__ float dkh_s[CSZ][DD];
  __shared__ float part[16][CSZ][DD];   // 64 KB partials (kh, then po)
  __shared__ float4 prm_s[CSZ];         // (theta, alpha, eta, -)

  float S[4], M[4];
#pragma unroll
  for (int r = 0; r < 4; r++) { S[r] = 0.f; M[r] = 0.f; }

  const float w_l = w[h * DD + l];
  const float b_l = bparm[h * DD + l];

  float* qbase = qkv + (size_t)(b * TT) * 3072 + h * DD;
  const float* pbase = p + (size_t)(b * TT) * 48 + h * 3;

  // ---- prologue: load + commit chunk 0 ----
  float rq, rk, rv, rp0 = 0.f, rp1 = 0.f, rp2 = 0.f;
  {
    size_t roff = (size_t)wv * 3072 + l;
    rq = qbase[roff];
    rk = qbase[roff + 1024];
    rv = qbase[roff + 2048];
    if (tid < CSZ) {
      const float* pp = pbase + (size_t)tid * 48;
      rp0 = pp[0]; rp1 = pp[1]; rp2 = pp[2];
    }
    q_s[wv][l] = rq; k_s[wv][l] = rk; v_s[wv][l] = rv;
    if (tid < CSZ)
      prm_s[tid] = make_float4(sigmoidf_(rp0), sigmoidf_(rp1), sigmoidf_(rp2), 0.f);
  }
  __syncthreads();

  for (int nt = 0; nt < NTC; nt++) {
    // ---- prefetch next chunk into registers (latency hides under phases A-C) ----
    if (nt + 1 < NTC) {
      size_t roff = (size_t)((nt + 1) * CSZ + wv) * 3072 + l;
      rq = qbase[roff];
      rk = qbase[roff + 1024];
      rv = qbase[roff + 2048];
      if (tid < CSZ) {
        const float* pp = pbase + (size_t)((nt + 1) * CSZ + tid) * 48;
        rp0 = pp[0]; rp1 = pp[1]; rp2 = pp[2];
      }
    }

    // ---- phase A: kh partials — wave wv contributes its 4 S-rows for all 16 tokens ----
#pragma unroll
    for (int c = 0; c < CSZ; c++) {
      float4 kf = *(const float4*)&k_s[c][wv * 4];   // broadcast read
      part[wv][c][l] = kf.x * S[0] + kf.y * S[1] + kf.z * S[2] + kf.w * S[3];
    }
    __syncthreads();

    // ---- phase B: LN fwd + bwd — one token row per wave ----
    {
      const int c = wv;
      float kh = 0.f;
#pragma unroll
      for (int ww = 0; ww < 16; ww++) kh += part[ww][c][l];
      float mu = wave_sum(kh) * (1.f / 64.f);
      float xc = kh - mu;
      float var = wave_sum(xc * xc) * (1.f / 64.f);
      float rstd = rsqrtf(var + EPSF);
      float xhat = xc * rstd;
      float y = xhat * w_l + b_l;
      float dy = 2.f * (y - v_s[c][l]);
      float wdy = dy * w_l;
      float c1 = wave_sum(xhat * wdy) * (1.f / 64.f);
      float c2 = wave_sum(wdy) * (1.f / 64.f);
      dkh_s[c][l] = (wdy - xhat * c1 - c2) * rstd;
    }
    __syncthreads();

    // ---- phase C: token scan — m = eta*m - theta*(k ⊗ dkh); S = (1-alpha)*S + m; po = q_t @ S_t ----
#pragma unroll
    for (int t = 0; t < CSZ; t++) {
      float4 prm = prm_s[t];
      float th = prm.x, al = prm.y, et = prm.z;
      float a = th * dkh_s[t][l];
      float bet = 1.f - al;
      float4 kf = *(const float4*)&k_s[t][wv * 4];
      float4 qf = *(const float4*)&q_s[t][wv * 4];
      float po;
      M[0] = et * M[0] - a * kf.x;  S[0] = bet * S[0] + M[0];  po  = qf.x * S[0];
      M[1] = et * M[1] - a * kf.y;  S[1] = bet * S[1] + M[1];  po += qf.y * S[1];
      M[2] = et * M[2] - a * kf.z;  S[2] = bet * S[2] + M[2];  po += qf.z * S[2];
      M[3] = et * M[3] - a * kf.w;  S[3] = bet * S[3] + M[3];  po += qf.w * S[3];
      part[wv][t][l] = po;
    }
    __syncthreads();

    // ---- phase D: o reduce + final LN + store; commit prefetched tiles to LDS ----
    {
      const int t = wv;
      float o = 0.f;
#pragma unroll
      for (int ww = 0; ww < 16; ww++) o += part[ww][t][l];
      float mu = wave_sum(o) * (1.f / 64.f);
      float xc = o - mu;
      float var = wave_sum(xc * xc) * (1.f / 64.f);
      float rstd = rsqrtf(var + EPSF);
      float y = xc * rstd * w_l + b_l;
      qbase[(size_t)(nt * CSZ + t) * 3072 + 2048 + l] = y;
      if (nt + 1 < NTC) {
        q_s[wv][l] = rq; k_s[wv][l] = rk; v_s[wv][l] = rv;
        if (tid < CSZ)
          prm_s[tid] = make_float4(sigmoidf_(rp0), sigmoidf_(rp1), sigmoidf_(rp2), 0.f);
      }
    }
    __syncthreads();
  }
}

extern "C" void kernel_launch(void* const* d_in, const int* in_sizes, int n_in,
                              void* d_out, int out_size, void* d_ws, size_t ws_size,
                              hipStream_t stream) {
  const float* x      = (const float*)d_in[0];
  const float* W_attn = (const float*)d_in[1];
  const float* b_attn = (const float*)d_in[2];
  const float* W_parm = (const float*)d_in[3];
  const float* b_parm = (const float*)d_in[4];
  const float* W_proj = (const float*)d_in[5];
  const float* b_proj = (const float*)d_in[6];
  const float* w      = (const float*)d_in[7];
  const float* bb     = (const float*)d_in[8];
  float* out = (float*)d_out;

  const int M = BB * TT;        // 8192
  float* qkv = (float*)d_ws;                          // M x 3072
  float* pbf = qkv + (size_t)M * 3072;                // M x 48

  // qkv = x @ W_attn + b_attn
  gemm_f32<<<dim3(3072 / 128, M / 128), 256, 0, stream>>>(x, CCH, W_attn, b_attn, qkv, M, 3072, CCH);
  // p = x @ W_param + b_param (sigmoid applied at use)
  gemm_f32<<<dim3(1, M / 128), 256, 0, stream>>>(x, CCH, W_parm, b_parm, pbf, M, 48, CCH);
  // L2 normalize q, k rows
  normalize_qk<<<(M * 2 * HH) / 4, 256, 0, stream>>>(qkv);
  // recurrence; writes LN(o) into v-slot (col offset 2048)
  titans_rec<<<BB * HH, 1024, 0, stream>>>(qkv, pbf, w, bb);
  // out = o @ W_proj + b_proj  (A = v-slot, lda = 3072)
  gemm_f32<<<dim3(CCH / 128, M / 128), 256, 0, stream>>>(qkv + 2048, 3072, W_proj, b_proj, out, M, CCH, CCH);
}

// Round 2
// 1777.504 us; speedup vs baseline: 1.3248x; 1.0379x over previous
//
#include <hip/hip_runtime.h>
#include <cstddef>
#include <cstdint>
#include <math.h>

#define BB   4
#define TT   2048
#define CCH  1024
#define HH   16
#define DD   64
#define CSZ  16
#define NTC  128
#define EPSF 1e-5f

__device__ __forceinline__ float wave_sum(float v) {
#pragma unroll
  for (int off = 32; off > 0; off >>= 1) v += __shfl_xor(v, off, 64);
  return v;
}

__device__ __forceinline__ float sigmoidf_(float x) {
  return 1.f / (1.f + expf(-x));
}

// C = A(lda) @ W + bias ; A: MxK row-major w/ stride lda, W: KxN row-major, C: MxN (ldc = N)
// M % 128 == 0, K % 16 == 0. N bounds-checked.
// Register-prefetch double-buffering: next tile's global loads are issued right after
// the LDS-commit barrier and consumed after the 16-kk compute (~2800 issue-cycles of
// latency cover), so the vmcnt(0) drain at the post-compute barrier is hidden.
__global__ __launch_bounds__(256) void gemm_f32(
    const float* __restrict__ A, int lda,
    const float* __restrict__ W,
    const float* __restrict__ bias,
    float* __restrict__ C, int M, int N, int K) {
  __shared__ float As[16][132];   // [k][m], padded to break store conflicts
  __shared__ float Bs[16][128];   // [k][n]
  const int tid  = threadIdx.x;
  const int row0 = blockIdx.y * 128;
  const int col0 = blockIdx.x * 128;
  const int ty = tid >> 4;         // 0..15 (m dir)
  const int tx = tid & 15;         // 0..15 (n dir)
  const int a_r = tid >> 2;        // 0..63
  const int a_k = (tid & 3) << 2;  // 0,4,8,12
  const int b_r = tid >> 5;        // 0..7
  const int b_c = (tid & 31) << 2; // 0..124

  float acc[8][8];
#pragma unroll
  for (int i = 0; i < 8; i++)
#pragma unroll
    for (int j = 0; j < 8; j++) acc[i][j] = 0.f;

  float4 areg[2], breg[2];
  const int gc = col0 + b_c;
#pragma unroll
  for (int i = 0; i < 2; i++)
    areg[i] = *(const float4*)(A + (size_t)(row0 + a_r + i * 64) * lda + a_k);
#pragma unroll
  for (int i = 0; i < 2; i++) {
    breg[i] = make_float4(0.f, 0.f, 0.f, 0.f);
    if (gc < N) breg[i] = *(const float4*)(W + (size_t)(b_r + i * 8) * N + gc);
  }

  for (int k0 = 0; k0 < K; k0 += 16) {
    // commit staged tile to LDS
#pragma unroll
    for (int i = 0; i < 2; i++) {
      int r = a_r + i * 64;
      As[a_k + 0][r] = areg[i].x;
      As[a_k + 1][r] = areg[i].y;
      As[a_k + 2][r] = areg[i].z;
      As[a_k + 3][r] = areg[i].w;
    }
#pragma unroll
    for (int i = 0; i < 2; i++) *(float4*)(&Bs[b_r + i * 8][b_c]) = breg[i];
    __syncthreads();

    // prefetch next tile (in flight across the compute below)
    if (k0 + 16 < K) {
#pragma unroll
      for (int i = 0; i < 2; i++)
        areg[i] = *(const float4*)(A + (size_t)(row0 + a_r + i * 64) * lda + (k0 + 16 + a_k));
#pragma unroll
      for (int i = 0; i < 2; i++) {
        breg[i] = make_float4(0.f, 0.f, 0.f, 0.f);
        if (gc < N) breg[i] = *(const float4*)(W + (size_t)(k0 + 16 + b_r + i * 8) * N + gc);
      }
    }

#pragma unroll
    for (int kk = 0; kk < 16; kk++) {
      float af[8], bf[8];
      *(float4*)&af[0] = *(const float4*)&As[kk][ty * 8];
      *(float4*)&af[4] = *(const float4*)&As[kk][ty * 8 + 4];
      *(float4*)&bf[0] = *(const float4*)&Bs[kk][tx * 8];
      *(float4*)&bf[4] = *(const float4*)&Bs[kk][tx * 8 + 4];
#pragma unroll
      for (int i = 0; i < 8; i++)
#pragma unroll
        for (int j = 0; j < 8; j++) acc[i][j] += af[i] * bf[j];
    }
    __syncthreads();
  }
#pragma unroll
  for (int i = 0; i < 8; i++) {
    int r = row0 + ty * 8 + i;
#pragma unroll
    for (int j0 = 0; j0 < 8; j0 += 4) {
      int cc = col0 + tx * 8 + j0;
      if (cc < N) {
        float4 ov;
        ov.x = acc[i][j0 + 0] + bias[cc + 0];
        ov.y = acc[i][j0 + 1] + bias[cc + 1];
        ov.z = acc[i][j0 + 2] + bias[cc + 2];
        ov.w = acc[i][j0 + 3] + bias[cc + 3];
        *(float4*)(C + (size_t)r * N + cc) = ov;
      }
    }
  }
}

// L2-normalize q and k rows (length 64) in-place inside the qkv buffer.
// One wave per row. rows = B*T*2*H.
__global__ __launch_bounds__(256) void normalize_qk(float* __restrict__ qkv) {
  const int idx = blockIdx.x * 4 + (threadIdx.x >> 6);
  const int l = threadIdx.x & 63;
  const int rowBT = idx >> 5;        // / (2*H)
  const int rem = idx & 31;
  const int which = rem >> 4;        // 0 = q, 1 = k
  const int h = rem & 15;
  const size_t addr = (size_t)rowBT * 3072 + (size_t)which * 1024 + h * 64 + l;
  float v = qkv[addr];
  float ss = wave_sum(v * v);
  float nrm = sqrtf(ss);
  float sc = 1.f / fmaxf(nrm, 1e-12f);
  qkv[addr] = v * sc;
}

// Titans recurrence. One block per (b,h). 1024 threads = 16 waves.
// Pipelined 3-barrier chunk loop:
//   A: kh partials for chunk nt  +  deferred o-reduce/LN/store of chunk nt-1
//   B: LN fwd+bwd -> dkh
//   C: commit chunk nt+1 tiles (dbuf), issue chunk nt+2 prefetch (drains at C's
//      barrier, hidden under the scan), token scan -> po partials
// part[] is double-buffered: chunk nt's kh AND po live in part[nt&1] (po overwrites
// kh after B); phase A of nt+1 reads po from part[nt&1] while writing kh to part[~nt&1].
__global__ __launch_bounds__(1024) void titans_rec(
    float* __restrict__ qkv, const float* __restrict__ p,
    const float* __restrict__ w, const float* __restrict__ bparm) {
  const int bh = blockIdx.x;
  const int b = bh >> 4;
  const int h = bh & 15;
  const int tid = threadIdx.x;
  const int wv = tid >> 6;   // 0..15
  const int l = tid & 63;

  __shared__ float k_s[2][CSZ][DD];      // 8 KB
  __shared__ float q_s[2][CSZ][DD];      // 8 KB
  __shared__ float v_s[CSZ][DD];         // 4 KB
  __shared__ float dkh_s[CSZ][DD];       // 4 KB
  __shared__ float part[2][16][CSZ][DD]; // 128 KB
  __shared__ float4 prm_s[2][CSZ];       // 0.5 KB  -> total ~152.5 KB (1 block/CU; only 64 blocks exist)

  float S[4], M[4];
#pragma unroll
  for (int r = 0; r < 4; r++) { S[r] = 0.f; M[r] = 0.f; }

  const float w_l = w[h * DD + l];
  const float b_l = bparm[h * DD + l];

  float* qbase = qkv + (size_t)(b * TT) * 3072 + h * DD;
  const float* pbase = p + (size_t)(b * TT) * 48 + h * 3;

  float rq, rk, rv, rp0 = 0.f, rp1 = 0.f, rp2 = 0.f;
  // ---- prologue: load + commit chunk 0; load chunk 1 into regs ----
  {
    size_t roff = (size_t)wv * 3072 + l;
    rq = qbase[roff];
    rk = qbase[roff + 1024];
    rv = qbase[roff + 2048];
    float p0 = 0.f, p1 = 0.f, p2 = 0.f;
    if (tid < CSZ) {
      const float* pp = pbase + (size_t)tid * 48;
      p0 = pp[0]; p1 = pp[1]; p2 = pp[2];
    }
    k_s[0][wv][l] = rk; q_s[0][wv][l] = rq; v_s[wv][l] = rv;
    if (tid < CSZ)
      prm_s[0][tid] = make_float4(sigmoidf_(p0), sigmoidf_(p1), sigmoidf_(p2), 0.f);
    roff = (size_t)(CSZ + wv) * 3072 + l;
    rq = qbase[roff];
    rk = qbase[roff + 1024];
    rv = qbase[roff + 2048];
    if (tid < CSZ) {
      const float* pp = pbase + (size_t)(CSZ + tid) * 48;
      rp0 = pp[0]; rp1 = pp[1]; rp2 = pp[2];
    }
  }
  __syncthreads();

  for (int nt = 0; nt < NTC; nt++) {
    const int buf = nt & 1;
    float (*partw)[CSZ][DD] = part[buf];       // this chunk's kh, then po
    float (*partr)[CSZ][DD] = part[buf ^ 1];   // previous chunk's po

    // ---- phase A: kh partials; deferred D of chunk nt-1 ----
#pragma unroll
    for (int c = 0; c < CSZ; c++) {
      float4 kf = *(const float4*)&k_s[buf][c][wv * 4];   // broadcast read
      partw[wv][c][l] = kf.x * S[0] + kf.y * S[1] + kf.z * S[2] + kf.w * S[3];
    }
    if (nt > 0) {
      const int t = wv;
      float o0 = 0.f, o1 = 0.f, o2 = 0.f, o3 = 0.f;
#pragma unroll
      for (int ww = 0; ww < 16; ww += 4) {
        o0 += partr[ww + 0][t][l];
        o1 += partr[ww + 1][t][l];
        o2 += partr[ww + 2][t][l];
        o3 += partr[ww + 3][t][l];
      }
      float o = (o0 + o1) + (o2 + o3);
      float mu = wave_sum(o) * (1.f / 64.f);
      float xc = o - mu;
      float var = wave_sum(xc * xc) * (1.f / 64.f);
      float rstd = rsqrtf(var + EPSF);
      float y = xc * rstd * w_l + b_l;
      qbase[(size_t)((nt - 1) * CSZ + t) * 3072 + 2048 + l] = y;
    }
    __syncthreads();

    // ---- phase B: LN fwd + bwd — one token row per wave ----
    {
      const int c = wv;
      float s0 = 0.f, s1 = 0.f, s2 = 0.f, s3 = 0.f;
#pragma unroll
      for (int ww = 0; ww < 16; ww += 4) {
        s0 += partw[ww + 0][c][l];
        s1 += partw[ww + 1][c][l];
        s2 += partw[ww + 2][c][l];
        s3 += partw[ww + 3][c][l];
      }
      float kh = (s0 + s1) + (s2 + s3);
      float mu = wave_sum(kh) * (1.f / 64.f);
      float xc = kh - mu;
      float var = wave_sum(xc * xc) * (1.f / 64.f);
      float rstd = rsqrtf(var + EPSF);
      float xhat = xc * rstd;
      float y = xhat * w_l + b_l;
      float dy = 2.f * (y - v_s[c][l]);
      float wdy = dy * w_l;
      float c1 = wave_sum(xhat * wdy) * (1.f / 64.f);
      float c2 = wave_sum(wdy) * (1.f / 64.f);
      dkh_s[c][l] = (wdy - xhat * c1 - c2) * rstd;
    }
    __syncthreads();

    // ---- phase C: commit next tiles, issue prefetch, token scan ----
    if (nt + 1 < NTC) {
      k_s[buf ^ 1][wv][l] = rk;
      q_s[buf ^ 1][wv][l] = rq;
      v_s[wv][l] = rv;
      if (tid < CSZ)
        prm_s[buf ^ 1][tid] = make_float4(sigmoidf_(rp0), sigmoidf_(rp1), sigmoidf_(rp2), 0.f);
    }
    if (nt + 2 < NTC) {
      size_t roff = (size_t)((nt + 2) * CSZ + wv) * 3072 + l;
      rq = qbase[roff];
      rk = qbase[roff + 1024];
      rv = qbase[roff + 2048];
      if (tid < CSZ) {
        const float* pp = pbase + (size_t)((nt + 2) * CSZ + tid) * 48;
        rp0 = pp[0]; rp1 = pp[1]; rp2 = pp[2];
      }
    }
#pragma unroll
    for (int t = 0; t < CSZ; t++) {
      float4 prm = prm_s[buf][t];
      float th = prm.x, al = prm.y, et = prm.z;
      float a = th * dkh_s[t][l];
      float bet = 1.f - al;
      float4 kf = *(const float4*)&k_s[buf][t][wv * 4];
      float4 qf = *(const float4*)&q_s[buf][t][wv * 4];
      float po;
      M[0] = et * M[0] - a * kf.x;  S[0] = bet * S[0] + M[0];  po  = qf.x * S[0];
      M[1] = et * M[1] - a * kf.y;  S[1] = bet * S[1] + M[1];  po += qf.y * S[1];
      M[2] = et * M[2] - a * kf.z;  S[2] = bet * S[2] + M[2];  po += qf.z * S[2];
      M[3] = et * M[3] - a * kf.w;  S[3] = bet * S[3] + M[3];  po += qf.w * S[3];
      partw[wv][t][l] = po;
    }
    __syncthreads();
  }

  // ---- epilogue: deferred D for the last chunk ----
  {
    const int t = wv;
    float (*partr)[CSZ][DD] = part[(NTC - 1) & 1];
    float o0 = 0.f, o1 = 0.f, o2 = 0.f, o3 = 0.f;
#pragma unroll
    for (int ww = 0; ww < 16; ww += 4) {
      o0 += partr[ww + 0][t][l];
      o1 += partr[ww + 1][t][l];
      o2 += partr[ww + 2][t][l];
      o3 += partr[ww + 3][t][l];
    }
    float o = (o0 + o1) + (o2 + o3);
    float mu = wave_sum(o) * (1.f / 64.f);
    float xc = o - mu;
    float var = wave_sum(xc * xc) * (1.f / 64.f);
    float rstd = rsqrtf(var + EPSF);
    float y = xc * rstd * w_l + b_l;
    qbase[(size_t)((NTC - 1) * CSZ + t) * 3072 + 2048 + l] = y;
  }
}

extern "C" void kernel_launch(void* const* d_in, const int* in_sizes, int n_in,
                              void* d_out, int out_size, void* d_ws, size_t ws_size,
                              hipStream_t stream) {
  const float* x      = (const float*)d_in[0];
  const float* W_attn = (const float*)d_in[1];
  const float* b_attn = (const float*)d_in[2];
  const float* W_parm = (const float*)d_in[3];
  const float* b_parm = (const float*)d_in[4];
  const float* W_proj = (const float*)d_in[5];
  const float* b_proj = (const float*)d_in[6];
  const float* w      = (const float*)d_in[7];
  const float* bb     = (const float*)d_in[8];
  float* out = (float*)d_out;

  const int M = BB * TT;        // 8192
  float* qkv = (float*)d_ws;                          // M x 3072
  float* pbf = qkv + (size_t)M * 3072;                // M x 48

  // qkv = x @ W_attn + b_attn
  gemm_f32<<<dim3(3072 / 128, M / 128), 256, 0, stream>>>(x, CCH, W_attn, b_attn, qkv, M, 3072, CCH);
  // p = x @ W_param + b_param (sigmoid applied at use)
  gemm_f32<<<dim3(1, M / 128), 256, 0, stream>>>(x, CCH, W_parm, b_parm, pbf, M, 48, CCH);
  // L2 normalize q, k rows
  normalize_qk<<<(M * 2 * HH) / 4, 256, 0, stream>>>(qkv);
  // recurrence; writes LN(o) into v-slot (col offset 2048)
  titans_rec<<<BB * HH, 1024, 0, stream>>>(qkv, pbf, w, bb);
  // out = o @ W_proj + b_proj  (A = v-slot, lda = 3072)
  gemm_f32<<<dim3(CCH / 128, M / 128), 256, 0, stream>>>(qkv + 2048, 3072, W_proj, b_proj, out, M, CCH, CCH);
}

// Round 3
// 1543.640 us; speedup vs baseline: 1.5255x; 1.1515x over previous
//
#include <hip/hip_runtime.h>
#include <cstddef>
#include <cstdint>
#include <math.h>

#define BB   4
#define TT   2048
#define CCH  1024
#define HH   16
#define DD   64
#define CSZ  16
#define NTC  128
#define EPSF 1e-5f
#define WVS  8

// Wave64 sum via DPP (VALU pipe, not LDS pipe like __shfl_xor/ds_swizzle).
// row_shr 1/2/4/8 within 16-lane rows, then row_bcast:15 (rows 1,3) and
// row_bcast:31 (rows 2,3); total lands in lane 63; readlane broadcasts via SGPR.
__device__ __forceinline__ float wave_sum(float x) {
  float v = x;
  v += __int_as_float(__builtin_amdgcn_update_dpp(0, __float_as_int(v), 0x111, 0xf, 0xf, true));
  v += __int_as_float(__builtin_amdgcn_update_dpp(0, __float_as_int(v), 0x112, 0xf, 0xf, true));
  v += __int_as_float(__builtin_amdgcn_update_dpp(0, __float_as_int(v), 0x114, 0xf, 0xf, true));
  v += __int_as_float(__builtin_amdgcn_update_dpp(0, __float_as_int(v), 0x118, 0xf, 0xf, true));
  v += __int_as_float(__builtin_amdgcn_update_dpp(0, __float_as_int(v), 0x142, 0xa, 0xf, true));
  v += __int_as_float(__builtin_amdgcn_update_dpp(0, __float_as_int(v), 0x143, 0xc, 0xf, true));
  return __int_as_float(__builtin_amdgcn_readlane(__float_as_int(v), 63));
}

__device__ __forceinline__ float sigmoidf_(float x) {
  return 1.f / (1.f + expf(-x));
}

// C = A(lda) @ W + bias ; A: MxK row-major w/ stride lda, W: KxN row-major, C: MxN (ldc = N)
// M % 128 == 0, K % 16 == 0. N bounds-checked. Register-prefetch double-buffered.
__global__ __launch_bounds__(256) void gemm_f32(
    const float* __restrict__ A, int lda,
    const float* __restrict__ W,
    const float* __restrict__ bias,
    float* __restrict__ C, int M, int N, int K) {
  __shared__ float As[16][132];   // [k][m], padded to break store conflicts
  __shared__ float Bs[16][128];   // [k][n]
  const int tid  = threadIdx.x;
  const int row0 = blockIdx.y * 128;
  const int col0 = blockIdx.x * 128;
  const int ty = tid >> 4;         // 0..15 (m dir)
  const int tx = tid & 15;         // 0..15 (n dir)
  const int a_r = tid >> 2;        // 0..63
  const int a_k = (tid & 3) << 2;  // 0,4,8,12
  const int b_r = tid >> 5;        // 0..7
  const int b_c = (tid & 31) << 2; // 0..124

  float acc[8][8];
#pragma unroll
  for (int i = 0; i < 8; i++)
#pragma unroll
    for (int j = 0; j < 8; j++) acc[i][j] = 0.f;

  float4 areg[2], breg[2];
  const int gc = col0 + b_c;
#pragma unroll
  for (int i = 0; i < 2; i++)
    areg[i] = *(const float4*)(A + (size_t)(row0 + a_r + i * 64) * lda + a_k);
#pragma unroll
  for (int i = 0; i < 2; i++) {
    breg[i] = make_float4(0.f, 0.f, 0.f, 0.f);
    if (gc < N) breg[i] = *(const float4*)(W + (size_t)(b_r + i * 8) * N + gc);
  }

  for (int k0 = 0; k0 < K; k0 += 16) {
#pragma unroll
    for (int i = 0; i < 2; i++) {
      int r = a_r + i * 64;
      As[a_k + 0][r] = areg[i].x;
      As[a_k + 1][r] = areg[i].y;
      As[a_k + 2][r] = areg[i].z;
      As[a_k + 3][r] = areg[i].w;
    }
#pragma unroll
    for (int i = 0; i < 2; i++) *(float4*)(&Bs[b_r + i * 8][b_c]) = breg[i];
    __syncthreads();

    if (k0 + 16 < K) {
#pragma unroll
      for (int i = 0; i < 2; i++)
        areg[i] = *(const float4*)(A + (size_t)(row0 + a_r + i * 64) * lda + (k0 + 16 + a_k));
#pragma unroll
      for (int i = 0; i < 2; i++) {
        breg[i] = make_float4(0.f, 0.f, 0.f, 0.f);
        if (gc < N) breg[i] = *(const float4*)(W + (size_t)(k0 + 16 + b_r + i * 8) * N + gc);
      }
    }

#pragma unroll
    for (int kk = 0; kk < 16; kk++) {
      float af[8], bf[8];
      *(float4*)&af[0] = *(const float4*)&As[kk][ty * 8];
      *(float4*)&af[4] = *(const float4*)&As[kk][ty * 8 + 4];
      *(float4*)&bf[0] = *(const float4*)&Bs[kk][tx * 8];
      *(float4*)&bf[4] = *(const float4*)&Bs[kk][tx * 8 + 4];
#pragma unroll
      for (int i = 0; i < 8; i++)
#pragma unroll
        for (int j = 0; j < 8; j++) acc[i][j] += af[i] * bf[j];
    }
    __syncthreads();
  }
#pragma unroll
  for (int i = 0; i < 8; i++) {
    int r = row0 + ty * 8 + i;
#pragma unroll
    for (int j0 = 0; j0 < 8; j0 += 4) {
      int cc = col0 + tx * 8 + j0;
      if (cc < N) {
        float4 ov;
        ov.x = acc[i][j0 + 0] + bias[cc + 0];
        ov.y = acc[i][j0 + 1] + bias[cc + 1];
        ov.z = acc[i][j0 + 2] + bias[cc + 2];
        ov.w = acc[i][j0 + 3] + bias[cc + 3];
        *(float4*)(C + (size_t)r * N + cc) = ov;
      }
    }
  }
}

// L2-normalize q and k rows (length 64) in-place inside the qkv buffer.
// One wave per row. rows = B*T*2*H.
__global__ __launch_bounds__(256) void normalize_qk(float* __restrict__ qkv) {
  const int idx = blockIdx.x * 4 + (threadIdx.x >> 6);
  const int l = threadIdx.x & 63;
  const int rowBT = idx >> 5;        // / (2*H)
  const int rem = idx & 31;
  const int which = rem >> 4;        // 0 = q, 1 = k
  const int h = rem & 15;
  const size_t addr = (size_t)rowBT * 3072 + (size_t)which * 1024 + h * 64 + l;
  float v = qkv[addr];
  float ss = wave_sum(v * v);
  float nrm = sqrtf(ss);
  float sc = 1.f / fmaxf(nrm, 1e-12f);
  qkv[addr] = v * sc;
}

// Titans recurrence. One block per (b,h). 512 threads = 8 waves, each wave owns
// 8 S/M rows (halves cross-wave `part` traffic + LDS broadcast count vs 16 waves;
// the kernel is LDS-pipe-throughput-bound, not latency- or issue-bound).
// 3-barrier pipelined chunk loop; wave_sum is DPP (VALU pipe).
__global__ __launch_bounds__(512) void titans_rec(
    float* __restrict__ qkv, const float* __restrict__ p,
    const float* __restrict__ w, const float* __restrict__ bparm) {
  const int bh = blockIdx.x;
  const int b = bh >> 4;
  const int h = bh & 15;
  const int tid = threadIdx.x;
  const int wv = tid >> 6;   // 0..7
  const int l = tid & 63;

  __shared__ float k_s[2][CSZ][DD];        // 8 KB
  __shared__ float q_s[2][CSZ][DD];        // 8 KB
  __shared__ float v_s[CSZ][DD];           // 4 KB
  __shared__ float dkh_s[CSZ][DD];         // 4 KB
  __shared__ float part[2][WVS][CSZ][DD];  // 64 KB
  __shared__ float4 prm_s[2][CSZ];         // 0.5 KB -> ~88.5 KB total

  float S[8], M[8];
#pragma unroll
  for (int r = 0; r < 8; r++) { S[r] = 0.f; M[r] = 0.f; }

  const float w_l = w[h * DD + l];
  const float b_l = bparm[h * DD + l];

  float* qbase = qkv + (size_t)(b * TT) * 3072 + h * DD;
  const float* pbase = p + (size_t)(b * TT) * 48 + h * 3;

  float rq[2], rk[2], rv[2], rp0 = 0.f, rp1 = 0.f, rp2 = 0.f;
  // ---- prologue: load + commit chunk 0; load chunk 1 into regs ----
  {
#pragma unroll
    for (int i = 0; i < 2; i++) {
      int row = wv + i * 8;
      size_t roff = (size_t)row * 3072 + l;
      q_s[0][row][l] = qbase[roff];
      k_s[0][row][l] = qbase[roff + 1024];
      v_s[row][l]    = qbase[roff + 2048];
    }
    if (tid < CSZ) {
      const float* pp = pbase + (size_t)tid * 48;
      prm_s[0][tid] = make_float4(sigmoidf_(pp[0]), sigmoidf_(pp[1]), sigmoidf_(pp[2]), 0.f);
    }
#pragma unroll
    for (int i = 0; i < 2; i++) {
      size_t roff = (size_t)(CSZ + wv + i * 8) * 3072 + l;
      rq[i] = qbase[roff];
      rk[i] = qbase[roff + 1024];
      rv[i] = qbase[roff + 2048];
    }
    if (tid < CSZ) {
      const float* pp = pbase + (size_t)(CSZ + tid) * 48;
      rp0 = pp[0]; rp1 = pp[1]; rp2 = pp[2];
    }
  }
  __syncthreads();

  for (int nt = 0; nt < NTC; nt++) {
    const int buf = nt & 1;
    float (*partw)[CSZ][DD] = part[buf];       // this chunk's kh, then po
    float (*partr)[CSZ][DD] = part[buf ^ 1];   // previous chunk's po

    // ---- phase A: deferred o/LN/store of chunk nt-1 first (store drain covered
    //      by the kh FMAs below), then kh partials for chunk nt ----
    if (nt > 0) {
#pragma unroll
      for (int i = 0; i < 2; i++) {
        const int t = wv + i * 8;
        float o = 0.f;
#pragma unroll
        for (int ww = 0; ww < WVS; ww++) o += partr[ww][t][l];
        float mu = wave_sum(o) * (1.f / 64.f);
        float xc = o - mu;
        float var = wave_sum(xc * xc) * (1.f / 64.f);
        float rstd = rsqrtf(var + EPSF);
        float y = xc * rstd * w_l + b_l;
        qbase[(size_t)((nt - 1) * CSZ + t) * 3072 + 2048 + l] = y;
      }
    }
#pragma unroll
    for (int c = 0; c < CSZ; c++) {
      const float* kp = &k_s[buf][c][wv * 8];
      float4 ka = *(const float4*)kp;          // broadcast reads
      float4 kb = *(const float4*)(kp + 4);
      partw[wv][c][l] = ka.x * S[0] + ka.y * S[1] + ka.z * S[2] + ka.w * S[3]
                      + kb.x * S[4] + kb.y * S[5] + kb.z * S[6] + kb.w * S[7];
    }
    __syncthreads();

    // ---- phase B: LN fwd + bwd — two token rows per wave ----
#pragma unroll
    for (int i = 0; i < 2; i++) {
      const int c = wv + i * 8;
      float kh = 0.f;
#pragma unroll
      for (int ww = 0; ww < WVS; ww++) kh += partw[ww][c][l];
      float mu = wave_sum(kh) * (1.f / 64.f);
      float xc = kh - mu;
      float var = wave_sum(xc * xc) * (1.f / 64.f);
      float rstd = rsqrtf(var + EPSF);
      float xhat = xc * rstd;
      float y = xhat * w_l + b_l;
      float dy = 2.f * (y - v_s[c][l]);
      float wdy = dy * w_l;
      float c1 = wave_sum(xhat * wdy) * (1.f / 64.f);
      float c2 = wave_sum(wdy) * (1.f / 64.f);
      dkh_s[c][l] = (wdy - xhat * c1 - c2) * rstd;
    }
    __syncthreads();

    // ---- phase C: commit next tiles, issue prefetch, token scan ----
    if (nt + 1 < NTC) {
#pragma unroll
      for (int i = 0; i < 2; i++) {
        int row = wv + i * 8;
        k_s[buf ^ 1][row][l] = rk[i];
        q_s[buf ^ 1][row][l] = rq[i];
        v_s[row][l] = rv[i];
      }
      if (tid < CSZ)
        prm_s[buf ^ 1][tid] = make_float4(sigmoidf_(rp0), sigmoidf_(rp1), sigmoidf_(rp2), 0.f);
    }
    if (nt + 2 < NTC) {
#pragma unroll
      for (int i = 0; i < 2; i++) {
        size_t roff = (size_t)((nt + 2) * CSZ + wv + i * 8) * 3072 + l;
        rq[i] = qbase[roff];
        rk[i] = qbase[roff + 1024];
        rv[i] = qbase[roff + 2048];
      }
      if (tid < CSZ) {
        const float* pp = pbase + (size_t)((nt + 2) * CSZ + tid) * 48;
        rp0 = pp[0]; rp1 = pp[1]; rp2 = pp[2];
      }
    }
#pragma unroll
    for (int t = 0; t < CSZ; t++) {
      float4 prm = prm_s[buf][t];
      float a = prm.x * dkh_s[t][l];
      float et = prm.z;
      float bet = 1.f - prm.y;
      const float* kp = &k_s[buf][t][wv * 8];
      const float* qp = &q_s[buf][t][wv * 8];
      float4 ka = *(const float4*)kp, kb = *(const float4*)(kp + 4);
      float4 qa = *(const float4*)qp, qb = *(const float4*)(qp + 4);
      float po;
      M[0] = et * M[0] - a * ka.x;  S[0] = bet * S[0] + M[0];  po  = qa.x * S[0];
      M[1] = et * M[1] - a * ka.y;  S[1] = bet * S[1] + M[1];  po += qa.y * S[1];
      M[2] = et * M[2] - a * ka.z;  S[2] = bet * S[2] + M[2];  po += qa.z * S[2];
      M[3] = et * M[3] - a * ka.w;  S[3] = bet * S[3] + M[3];  po += qa.w * S[3];
      M[4] = et * M[4] - a * kb.x;  S[4] = bet * S[4] + M[4];  po += qb.x * S[4];
      M[5] = et * M[5] - a * kb.y;  S[5] = bet * S[5] + M[5];  po += qb.y * S[5];
      M[6] = et * M[6] - a * kb.z;  S[6] = bet * S[6] + M[6];  po += qb.z * S[6];
      M[7] = et * M[7] - a * kb.w;  S[7] = bet * S[7] + M[7];  po += qb.w * S[7];
      partw[wv][t][l] = po;
    }
    __syncthreads();
  }

  // ---- epilogue: deferred D for the last chunk ----
  {
    float (*partr)[CSZ][DD] = part[(NTC - 1) & 1];
#pragma unroll
    for (int i = 0; i < 2; i++) {
      const int t = wv + i * 8;
      float o = 0.f;
#pragma unroll
      for (int ww = 0; ww < WVS; ww++) o += partr[ww][t][l];
      float mu = wave_sum(o) * (1.f / 64.f);
      float xc = o - mu;
      float var = wave_sum(xc * xc) * (1.f / 64.f);
      float rstd = rsqrtf(var + EPSF);
      float y = xc * rstd * w_l + b_l;
      qbase[(size_t)((NTC - 1) * CSZ + t) * 3072 + 2048 + l] = y;
    }
  }
}

extern "C" void kernel_launch(void* const* d_in, const int* in_sizes, int n_in,
                              void* d_out, int out_size, void* d_ws, size_t ws_size,
                              hipStream_t stream) {
  const float* x      = (const float*)d_in[0];
  const float* W_attn = (const float*)d_in[1];
  const float* b_attn = (const float*)d_in[2];
  const float* W_parm = (const float*)d_in[3];
  const float* b_parm = (const float*)d_in[4];
  const float* W_proj = (const float*)d_in[5];
  const float* b_proj = (const float*)d_in[6];
  const float* w      = (const float*)d_in[7];
  const float* bb     = (const float*)d_in[8];
  float* out = (float*)d_out;

  const int M = BB * TT;        // 8192
  float* qkv = (float*)d_ws;                          // M x 3072
  float* pbf = qkv + (size_t)M * 3072;                // M x 48

  // qkv = x @ W_attn + b_attn
  gemm_f32<<<dim3(3072 / 128, M / 128), 256, 0, stream>>>(x, CCH, W_attn, b_attn, qkv, M, 3072, CCH);
  // p = x @ W_param + b_param (sigmoid applied at use)
  gemm_f32<<<dim3(1, M / 128), 256, 0, stream>>>(x, CCH, W_parm, b_parm, pbf, M, 48, CCH);
  // L2 normalize q, k rows
  normalize_qk<<<(M * 2 * HH) / 4, 256, 0, stream>>>(qkv);
  // recurrence; writes LN(o) into v-slot (col offset 2048)
  titans_rec<<<BB * HH, 512, 0, stream>>>(qkv, pbf, w, bb);
  // out = o @ W_proj + b_proj  (A = v-slot, lda = 3072)
  gemm_f32<<<dim3(CCH / 128, M / 128), 256, 0, stream>>>(qkv + 2048, 3072, W_proj, b_proj, out, M, CCH, CCH);
}

// Round 4
// 1057.366 us; speedup vs baseline: 2.2271x; 1.4599x over previous
//
#include <hip/hip_runtime.h>
#include <cstddef>
#include <cstdint>
#include <math.h>

#define BB   4
#define TT   2048
#define CCH  1024
#define HH   16
#define DD   64
#define CSZ  16
#define NTC  128
#define EPSF 1e-5f
#define WVS  8

typedef __attribute__((ext_vector_type(8))) short bf16x8;
typedef __attribute__((ext_vector_type(4))) float f32x4;

// ---------- split-float helpers: f32 ≈ hi(bf16) + lo(bf16), packed (hi | lo<<16) ----------
__device__ __forceinline__ uint32_t pack_split(float f) {
  uint32_t b = __float_as_uint(f);
  uint32_t uh = (b + 0x7fffu + ((b >> 16) & 1u)) >> 16;   // RNE bf16 of f
  float fh = __uint_as_float(uh << 16);
  float r = f - fh;
  return uh | (__float_as_uint(r) & 0xffff0000u);          // lo = trunc bf16 of residual
}
__device__ __forceinline__ float unpack_f(uint32_t u) {
  return __uint_as_float(u << 16) + __uint_as_float(u & 0xffff0000u);
}

// Wave64 sum via DPP (VALU pipe, not LDS pipe).
__device__ __forceinline__ float wave_sum(float x) {
  float v = x;
  v += __int_as_float(__builtin_amdgcn_update_dpp(0, __float_as_int(v), 0x111, 0xf, 0xf, true));
  v += __int_as_float(__builtin_amdgcn_update_dpp(0, __float_as_int(v), 0x112, 0xf, 0xf, true));
  v += __int_as_float(__builtin_amdgcn_update_dpp(0, __float_as_int(v), 0x114, 0xf, 0xf, true));
  v += __int_as_float(__builtin_amdgcn_update_dpp(0, __float_as_int(v), 0x118, 0xf, 0xf, true));
  v += __int_as_float(__builtin_amdgcn_update_dpp(0, __float_as_int(v), 0x142, 0xa, 0xf, true));
  v += __int_as_float(__builtin_amdgcn_update_dpp(0, __float_as_int(v), 0x143, 0xc, 0xf, true));
  return __int_as_float(__builtin_amdgcn_readlane(__float_as_int(v), 63));
}

__device__ __forceinline__ float sigmoidf_(float x) {
  return 1.f / (1.f + expf(-x));
}

// ---------- transpose + split: W (KxN f32) -> Wt (NxK packed u32) ----------
__global__ __launch_bounds__(256) void split_transpose(
    const float* __restrict__ W, uint32_t* __restrict__ Wt, int K, int N) {
  __shared__ float t[32][33];
  const int n0 = blockIdx.x * 32, k0 = blockIdx.y * 32;
  const int tx = threadIdx.x & 31, ty = threadIdx.x >> 5;  // ty 0..7
#pragma unroll
  for (int i = 0; i < 4; i++)
    t[ty + i * 8][tx] = W[(size_t)(k0 + ty + i * 8) * N + n0 + tx];
  __syncthreads();
#pragma unroll
  for (int i = 0; i < 4; i++)
    Wt[(size_t)(n0 + ty + i * 8) * K + k0 + tx] = pack_split(t[tx][ty + i * 8]);
}

// ---------- split-bf16 MFMA GEMM: C = A @ Bt^T + bias ----------
// A: MxK (f32, or packed u32 when A_PACKED), row stride lda (elements).
// Bt: NxK packed u32 (i.e. B^T, pre-split). M%128==0, N%128==0, K%32==0.
// acc += Ahi*Bhi + Ahi*Blo + Alo*Bhi  (3xbf16 ~ fp32 precision).
// C: packed u32 (C_PACKED) or f32.
template<bool A_PACKED, bool C_PACKED>
__global__ __launch_bounds__(256) void gemm_split(
    const void* __restrict__ Av, int lda,
    const uint32_t* __restrict__ Bt,
    const float* __restrict__ bias,
    void* __restrict__ Cv, int M, int N, int K) {
  __shared__ unsigned short Ahi[128][40];   // pad 32->40: 2-way banks (free)
  __shared__ unsigned short Alo[128][40];
  __shared__ unsigned short Bhi[128][40];
  __shared__ unsigned short Blo[128][40];

  const int tid = threadIdx.x;
  const int row0 = blockIdx.y * 128;
  const int col0 = blockIdx.x * 128;
  const int wv = tid >> 6;
  const int l  = tid & 63;
  const int wr = wv >> 1, wc = wv & 1;     // 2x2 wave grid, 64x64 per wave
  const int lrow = l & 15;
  const int kgrp = (l >> 4) * 8;           // A/B frag: 8 contiguous k per lane

  const int sr = tid >> 1;                 // staging row 0..127
  const int sk = (tid & 1) * 16;           // staging k offset 0/16

  f32x4 acc[4][4];
#pragma unroll
  for (int i = 0; i < 4; i++)
#pragma unroll
    for (int j = 0; j < 4; j++) acc[i][j] = (f32x4){0.f, 0.f, 0.f, 0.f};

  for (int k0 = 0; k0 < K; k0 += 32) {
    // ---- stage A (hi/lo planes) ----
    {
      uint32_t hp[8], lp[8];
      if (A_PACKED) {
        const uint32_t* Ap = (const uint32_t*)Av + (size_t)(row0 + sr) * lda + k0 + sk;
        uint32_t u[16];
#pragma unroll
        for (int i = 0; i < 4; i++) *(uint4*)&u[i * 4] = *(const uint4*)(Ap + i * 4);
#pragma unroll
        for (int j = 0; j < 8; j++) {
          hp[j] = (u[2 * j] & 0xffffu) | (u[2 * j + 1] << 16);
          lp[j] = (u[2 * j] >> 16) | (u[2 * j + 1] & 0xffff0000u);
        }
      } else {
        const float* Ap = (const float*)Av + (size_t)(row0 + sr) * lda + k0 + sk;
        float f[16];
#pragma unroll
        for (int i = 0; i < 4; i++) *(float4*)&f[i * 4] = *(const float4*)(Ap + i * 4);
        uint32_t uh[16], ulr[16];
#pragma unroll
        for (int j = 0; j < 16; j++) {
          uint32_t b = __float_as_uint(f[j]);
          uint32_t h = (b + 0x7fffu + ((b >> 16) & 1u)) >> 16;
          uh[j] = h;
          ulr[j] = __float_as_uint(f[j] - __uint_as_float(h << 16));
        }
#pragma unroll
        for (int j = 0; j < 8; j++) {
          hp[j] = uh[2 * j] | (uh[2 * j + 1] << 16);
          lp[j] = (ulr[2 * j] >> 16) | (ulr[2 * j + 1] & 0xffff0000u);
        }
      }
      *(uint4*)&Ahi[sr][sk]     = *(uint4*)&hp[0];
      *(uint4*)&Ahi[sr][sk + 8] = *(uint4*)&hp[4];
      *(uint4*)&Alo[sr][sk]     = *(uint4*)&lp[0];
      *(uint4*)&Alo[sr][sk + 8] = *(uint4*)&lp[4];
    }
    // ---- stage B ----
    {
      const uint32_t* Bp = Bt + (size_t)(col0 + sr) * K + k0 + sk;
      uint32_t u[16], hp[8], lp[8];
#pragma unroll
      for (int i = 0; i < 4; i++) *(uint4*)&u[i * 4] = *(const uint4*)(Bp + i * 4);
#pragma unroll
      for (int j = 0; j < 8; j++) {
        hp[j] = (u[2 * j] & 0xffffu) | (u[2 * j + 1] << 16);
        lp[j] = (u[2 * j] >> 16) | (u[2 * j + 1] & 0xffff0000u);
      }
      *(uint4*)&Bhi[sr][sk]     = *(uint4*)&hp[0];
      *(uint4*)&Bhi[sr][sk + 8] = *(uint4*)&hp[4];
      *(uint4*)&Blo[sr][sk]     = *(uint4*)&lp[0];
      *(uint4*)&Blo[sr][sk + 8] = *(uint4*)&lp[4];
    }
    __syncthreads();

    // ---- compute: 16 frag-pairs x 3 MFMA ----
    bf16x8 bh[4], bl[4];
#pragma unroll
    for (int j = 0; j < 4; j++) {
      bh[j] = *(const bf16x8*)&Bhi[wc * 64 + j * 16 + lrow][kgrp];
      bl[j] = *(const bf16x8*)&Blo[wc * 64 + j * 16 + lrow][kgrp];
    }
#pragma unroll
    for (int i = 0; i < 4; i++) {
      bf16x8 ah = *(const bf16x8*)&Ahi[wr * 64 + i * 16 + lrow][kgrp];
      bf16x8 al = *(const bf16x8*)&Alo[wr * 64 + i * 16 + lrow][kgrp];
#pragma unroll
      for (int j = 0; j < 4; j++) {
        acc[i][j] = __builtin_amdgcn_mfma_f32_16x16x32_bf16(ah, bh[j], acc[i][j], 0, 0, 0);
        acc[i][j] = __builtin_amdgcn_mfma_f32_16x16x32_bf16(ah, bl[j], acc[i][j], 0, 0, 0);
        acc[i][j] = __builtin_amdgcn_mfma_f32_16x16x32_bf16(al, bh[j], acc[i][j], 0, 0, 0);
      }
    }
    __syncthreads();
  }

  // ---- epilogue: C/D layout col=lane&15, row=(lane>>4)*4+reg ----
  const int crow4 = (l >> 4) * 4;
#pragma unroll
  for (int i = 0; i < 4; i++) {
#pragma unroll
    for (int j = 0; j < 4; j++) {
      const int col = col0 + wc * 64 + j * 16 + lrow;
      const float bv = bias[col];
      const int rowb = row0 + wr * 64 + i * 16 + crow4;
#pragma unroll
      for (int r = 0; r < 4; r++) {
        float v = acc[i][j][r] + bv;
        size_t off = (size_t)(rowb + r) * N + col;
        if (C_PACKED) ((uint32_t*)Cv)[off] = pack_split(v);
        else          ((float*)Cv)[off] = v;
      }
    }
  }
}

// ---------- fp32 VALU GEMM (kept only for the tiny N=48 param GEMM) ----------
__global__ __launch_bounds__(256) void gemm_f32(
    const float* __restrict__ A, int lda,
    const float* __restrict__ W,
    const float* __restrict__ bias,
    float* __restrict__ C, int M, int N, int K) {
  __shared__ float As[16][132];
  __shared__ float Bs[16][128];
  const int tid  = threadIdx.x;
  const int row0 = blockIdx.y * 128;
  const int col0 = blockIdx.x * 128;
  const int ty = tid >> 4;
  const int tx = tid & 15;
  const int a_r = tid >> 2;
  const int a_k = (tid & 3) << 2;
  const int b_r = tid >> 5;
  const int b_c = (tid & 31) << 2;

  float acc[8][8];
#pragma unroll
  for (int i = 0; i < 8; i++)
#pragma unroll
    for (int j = 0; j < 8; j++) acc[i][j] = 0.f;

  float4 areg[2], breg[2];
  const int gc = col0 + b_c;
#pragma unroll
  for (int i = 0; i < 2; i++)
    areg[i] = *(const float4*)(A + (size_t)(row0 + a_r + i * 64) * lda + a_k);
#pragma unroll
  for (int i = 0; i < 2; i++) {
    breg[i] = make_float4(0.f, 0.f, 0.f, 0.f);
    if (gc < N) breg[i] = *(const float4*)(W + (size_t)(b_r + i * 8) * N + gc);
  }

  for (int k0 = 0; k0 < K; k0 += 16) {
#pragma unroll
    for (int i = 0; i < 2; i++) {
      int r = a_r + i * 64;
      As[a_k + 0][r] = areg[i].x;
      As[a_k + 1][r] = areg[i].y;
      As[a_k + 2][r] = areg[i].z;
      As[a_k + 3][r] = areg[i].w;
    }
#pragma unroll
    for (int i = 0; i < 2; i++) *(float4*)(&Bs[b_r + i * 8][b_c]) = breg[i];
    __syncthreads();

    if (k0 + 16 < K) {
#pragma unroll
      for (int i = 0; i < 2; i++)
        areg[i] = *(const float4*)(A + (size_t)(row0 + a_r + i * 64) * lda + (k0 + 16 + a_k));
#pragma unroll
      for (int i = 0; i < 2; i++) {
        breg[i] = make_float4(0.f, 0.f, 0.f, 0.f);
        if (gc < N) breg[i] = *(const float4*)(W + (size_t)(k0 + 16 + b_r + i * 8) * N + gc);
      }
    }

#pragma unroll
    for (int kk = 0; kk < 16; kk++) {
      float af[8], bf[8];
      *(float4*)&af[0] = *(const float4*)&As[kk][ty * 8];
      *(float4*)&af[4] = *(const float4*)&As[kk][ty * 8 + 4];
      *(float4*)&bf[0] = *(const float4*)&Bs[kk][tx * 8];
      *(float4*)&bf[4] = *(const float4*)&Bs[kk][tx * 8 + 4];
#pragma unroll
      for (int i = 0; i < 8; i++)
#pragma unroll
        for (int j = 0; j < 8; j++) acc[i][j] += af[i] * bf[j];
    }
    __syncthreads();
  }
#pragma unroll
  for (int i = 0; i < 8; i++) {
    int r = row0 + ty * 8 + i;
#pragma unroll
    for (int j0 = 0; j0 < 8; j0 += 4) {
      int cc = col0 + tx * 8 + j0;
      if (cc < N) {
        float4 ov;
        ov.x = acc[i][j0 + 0] + bias[cc + 0];
        ov.y = acc[i][j0 + 1] + bias[cc + 1];
        ov.z = acc[i][j0 + 2] + bias[cc + 2];
        ov.w = acc[i][j0 + 3] + bias[cc + 3];
        *(float4*)(C + (size_t)r * N + cc) = ov;
      }
    }
  }
}

// L2-normalize packed q/k rows (length 64) in-place. One wave per row.
__global__ __launch_bounds__(256) void normalize_qk(uint32_t* __restrict__ qkv) {
  const int idx = blockIdx.x * 4 + (threadIdx.x >> 6);
  const int l = threadIdx.x & 63;
  const int rowBT = idx >> 5;
  const int rem = idx & 31;
  const int which = rem >> 4;
  const int h = rem & 15;
  const size_t addr = (size_t)rowBT * 3072 + (size_t)which * 1024 + h * 64 + l;
  float v = unpack_f(qkv[addr]);
  float ss = wave_sum(v * v);
  float sc = 1.f / fmaxf(sqrtf(ss), 1e-12f);
  qkv[addr] = pack_split(v * sc);
}

// Titans recurrence. One block per (b,h). 512 threads = 8 waves x 8 S-rows.
// q/k/v and o are split-packed u32 in the qkv buffer.
__global__ __launch_bounds__(512) void titans_rec(
    uint32_t* __restrict__ qkv, const float* __restrict__ p,
    const float* __restrict__ w, const float* __restrict__ bparm) {
  const int bh = blockIdx.x;
  const int b = bh >> 4;
  const int h = bh & 15;
  const int tid = threadIdx.x;
  const int wv = tid >> 6;   // 0..7
  const int l = tid & 63;

  __shared__ float k_s[2][CSZ][DD];
  __shared__ float q_s[2][CSZ][DD];
  __shared__ float v_s[CSZ][DD];
  __shared__ float dkh_s[CSZ][DD];
  __shared__ float part[2][WVS][CSZ][DD];
  __shared__ float4 prm_s[2][CSZ];

  float S[8], M[8];
#pragma unroll
  for (int r = 0; r < 8; r++) { S[r] = 0.f; M[r] = 0.f; }

  const float w_l = w[h * DD + l];
  const float b_l = bparm[h * DD + l];

  uint32_t* qbase = qkv + (size_t)(b * TT) * 3072 + h * DD;
  const float* pbase = p + (size_t)(b * TT) * 48 + h * 3;

  uint32_t rq[2], rk[2], rv[2];
  float rp0 = 0.f, rp1 = 0.f, rp2 = 0.f;
  {
#pragma unroll
    for (int i = 0; i < 2; i++) {
      int row = wv + i * 8;
      size_t roff = (size_t)row * 3072 + l;
      q_s[0][row][l] = unpack_f(qbase[roff]);
      k_s[0][row][l] = unpack_f(qbase[roff + 1024]);
      v_s[row][l]    = unpack_f(qbase[roff + 2048]);
    }
    if (tid < CSZ) {
      const float* pp = pbase + (size_t)tid * 48;
      prm_s[0][tid] = make_float4(sigmoidf_(pp[0]), sigmoidf_(pp[1]), sigmoidf_(pp[2]), 0.f);
    }
#pragma unroll
    for (int i = 0; i < 2; i++) {
      size_t roff = (size_t)(CSZ + wv + i * 8) * 3072 + l;
      rq[i] = qbase[roff];
      rk[i] = qbase[roff + 1024];
      rv[i] = qbase[roff + 2048];
    }
    if (tid < CSZ) {
      const float* pp = pbase + (size_t)(CSZ + tid) * 48;
      rp0 = pp[0]; rp1 = pp[1]; rp2 = pp[2];
    }
  }
  __syncthreads();

  for (int nt = 0; nt < NTC; nt++) {
    const int buf = nt & 1;
    float (*partw)[CSZ][DD] = part[buf];
    float (*partr)[CSZ][DD] = part[buf ^ 1];

    // ---- phase A: deferred o/LN/store of chunk nt-1, then kh partials ----
    if (nt > 0) {
#pragma unroll
      for (int i = 0; i < 2; i++) {
        const int t = wv + i * 8;
        float o = 0.f;
#pragma unroll
        for (int ww = 0; ww < WVS; ww++) o += partr[ww][t][l];
        float mu = wave_sum(o) * (1.f / 64.f);
        float xc = o - mu;
        float var = wave_sum(xc * xc) * (1.f / 64.f);
        float rstd = rsqrtf(var + EPSF);
        float y = xc * rstd * w_l + b_l;
        qbase[(size_t)((nt - 1) * CSZ + t) * 3072 + 2048 + l] = pack_split(y);
      }
    }
#pragma unroll
    for (int c = 0; c < CSZ; c++) {
      const float* kp = &k_s[buf][c][wv * 8];
      float4 ka = *(const float4*)kp;
      float4 kb = *(const float4*)(kp + 4);
      partw[wv][c][l] = ka.x * S[0] + ka.y * S[1] + ka.z * S[2] + ka.w * S[3]
                      + kb.x * S[4] + kb.y * S[5] + kb.z * S[6] + kb.w * S[7];
    }
    __syncthreads();

    // ---- phase B: LN fwd + bwd ----
#pragma unroll
    for (int i = 0; i < 2; i++) {
      const int c = wv + i * 8;
      float kh = 0.f;
#pragma unroll
      for (int ww = 0; ww < WVS; ww++) kh += partw[ww][c][l];
      float mu = wave_sum(kh) * (1.f / 64.f);
      float xc = kh - mu;
      float var = wave_sum(xc * xc) * (1.f / 64.f);
      float rstd = rsqrtf(var + EPSF);
      float xhat = xc * rstd;
      float y = xhat * w_l + b_l;
      float dy = 2.f * (y - v_s[c][l]);
      float wdy = dy * w_l;
      float c1 = wave_sum(xhat * wdy) * (1.f / 64.f);
      float c2 = wave_sum(wdy) * (1.f / 64.f);
      dkh_s[c][l] = (wdy - xhat * c1 - c2) * rstd;
    }
    __syncthreads();

    // ---- phase C: commit next tiles, issue prefetch, token scan ----
    if (nt + 1 < NTC) {
#pragma unroll
      for (int i = 0; i < 2; i++) {
        int row = wv + i * 8;
        k_s[buf ^ 1][row][l] = unpack_f(rk[i]);
        q_s[buf ^ 1][row][l] = unpack_f(rq[i]);
        v_s[row][l] = unpack_f(rv[i]);
      }
      if (tid < CSZ)
        prm_s[buf ^ 1][tid] = make_float4(sigmoidf_(rp0), sigmoidf_(rp1), sigmoidf_(rp2), 0.f);
    }
    if (nt + 2 < NTC) {
#pragma unroll
      for (int i = 0; i < 2; i++) {
        size_t roff = (size_t)((nt + 2) * CSZ + wv + i * 8) * 3072 + l;
        rq[i] = qbase[roff];
        rk[i] = qbase[roff + 1024];
        rv[i] = qbase[roff + 2048];
      }
      if (tid < CSZ) {
        const float* pp = pbase + (size_t)((nt + 2) * CSZ + tid) * 48;
        rp0 = pp[0]; rp1 = pp[1]; rp2 = pp[2];
      }
    }
#pragma unroll
    for (int t = 0; t < CSZ; t++) {
      float4 prm = prm_s[buf][t];
      float a = prm.x * dkh_s[t][l];
      float et = prm.z;
      float bet = 1.f - prm.y;
      const float* kp = &k_s[buf][t][wv * 8];
      const float* qp = &q_s[buf][t][wv * 8];
      float4 ka = *(const float4*)kp, kb = *(const float4*)(kp + 4);
      float4 qa = *(const float4*)qp, qb = *(const float4*)(qp + 4);
      float po;
      M[0] = et * M[0] - a * ka.x;  S[0] = bet * S[0] + M[0];  po  = qa.x * S[0];
      M[1] = et * M[1] - a * ka.y;  S[1] = bet * S[1] + M[1];  po += qa.y * S[1];
      M[2] = et * M[2] - a * ka.z;  S[2] = bet * S[2] + M[2];  po += qa.z * S[2];
      M[3] = et * M[3] - a * ka.w;  S[3] = bet * S[3] + M[3];  po += qa.w * S[3];
      M[4] = et * M[4] - a * kb.x;  S[4] = bet * S[4] + M[4];  po += qb.x * S[4];
      M[5] = et * M[5] - a * kb.y;  S[5] = bet * S[5] + M[5];  po += qb.y * S[5];
      M[6] = et * M[6] - a * kb.z;  S[6] = bet * S[6] + M[6];  po += qb.z * S[6];
      M[7] = et * M[7] - a * kb.w;  S[7] = bet * S[7] + M[7];  po += qb.w * S[7];
      partw[wv][t][l] = po;
    }
    __syncthreads();
  }

  // ---- epilogue: deferred D for the last chunk ----
  {
    float (*partr)[CSZ][DD] = part[(NTC - 1) & 1];
#pragma unroll
    for (int i = 0; i < 2; i++) {
      const int t = wv + i * 8;
      float o = 0.f;
#pragma unroll
      for (int ww = 0; ww < WVS; ww++) o += partr[ww][t][l];
      float mu = wave_sum(o) * (1.f / 64.f);
      float xc = o - mu;
      float var = wave_sum(xc * xc) * (1.f / 64.f);
      float rstd = rsqrtf(var + EPSF);
      float y = xc * rstd * w_l + b_l;
      qbase[(size_t)((NTC - 1) * CSZ + t) * 3072 + 2048 + l] = pack_split(y);
    }
  }
}

extern "C" void kernel_launch(void* const* d_in, const int* in_sizes, int n_in,
                              void* d_out, int out_size, void* d_ws, size_t ws_size,
                              hipStream_t stream) {
  const float* x      = (const float*)d_in[0];
  const float* W_attn = (const float*)d_in[1];
  const float* b_attn = (const float*)d_in[2];
  const float* W_parm = (const float*)d_in[3];
  const float* b_parm = (const float*)d_in[4];
  const float* W_proj = (const float*)d_in[5];
  const float* b_proj = (const float*)d_in[6];
  const float* w      = (const float*)d_in[7];
  const float* bb     = (const float*)d_in[8];
  float* out = (float*)d_out;

  const int M = BB * TT;        // 8192
  float* qkv = (float*)d_ws;                          // M x 3072 (packed u32 after qkv gemm)
  float* pbf = qkv + (size_t)M * 3072;                // M x 48 f32
  uint32_t* wattn_t = (uint32_t*)(pbf + (size_t)M * 48);   // 3072 x 1024 packed
  uint32_t* wproj_t = wattn_t + (size_t)3072 * 1024;       // 1024 x 1024 packed

  // pre-split + transpose weights (one-time, memory-bound)
  split_transpose<<<dim3(3072 / 32, 1024 / 32), 256, 0, stream>>>(W_attn, wattn_t, 1024, 3072);
  split_transpose<<<dim3(1024 / 32, 1024 / 32), 256, 0, stream>>>(W_proj, wproj_t, 1024, 1024);

  // qkv = x @ W_attn + b_attn  (A f32 split on the fly; C packed)
  gemm_split<false, true><<<dim3(3072 / 128, M / 128), 256, 0, stream>>>(
      x, CCH, wattn_t, b_attn, qkv, M, 3072, CCH);
  // p = x @ W_param + b_param (fp32 VALU; sigmoid applied at use)
  gemm_f32<<<dim3(1, M / 128), 256, 0, stream>>>(x, CCH, W_parm, b_parm, pbf, M, 48, CCH);
  // L2 normalize q, k rows (packed in/out)
  normalize_qk<<<(M * 2 * HH) / 4, 256, 0, stream>>>((uint32_t*)qkv);
  // recurrence; writes packed LN(o) into v-slot
  titans_rec<<<BB * HH, 512, 0, stream>>>((uint32_t*)qkv, pbf, w, bb);
  // out = o @ W_proj + b_proj  (A packed from v-slot; C f32)
  gemm_split<true, false><<<dim3(CCH / 128, M / 128), 256, 0, stream>>>(
      (uint32_t*)qkv + 2048, 3072, wproj_t, b_proj, out, M, CCH, CCH);
}